// Round 2
// baseline (228.118 us; speedup 1.0000x reference)
//
#include <hip/hip_runtime.h>

// YOLO 1D (audio) detection decoder, CENTER_DURATION encoding.
// Input  x: [B=32, G=131072, F=8] fp32. Output: fragments [B,G,7] fp32 then
// mask [B,G] fp32 (1.0/0.0), concatenated flat in d_out.
//
// Memory-bound: 128 MiB in + 128 MiB out → ~40 µs floor at 6.4 TB/s.
// R2: 2 cells/thread (more MLP), float4 write-back sweeps via LDS
// (896 b128 stores per block instead of 3584 dword stores), mask stored
// directly (already stride-1 coalesced). __fadd_rn/__fmul_rn block FMA
// contraction so rintf (= jnp.round, round-half-even) matches JAX bit-exactly
// (absmax was 0.0 in R1 — numerics path unchanged).

constexpr int BLOCK = 256;
constexpr int CPB   = 512;   // cells per block (2 per thread)
constexpr int F_OUT = 7;

__global__ __launch_bounds__(BLOCK) void yolo_decode_kernel(
    const float4* __restrict__ in,    // [total_cells * 2] float4
    float* __restrict__ frag,         // [total_cells * 7]
    float* __restrict__ mask_out,     // [total_cells]
    int g_mask,                       // G - 1 (G is a power of two)
    float cell_coef,                  // INPUT_LENGTH / G   (= 8.0f)
    float unbind_coef)                // INPUT_LENGTH       (= 1048576.0f)
{
    __shared__ float s_frag[CPB * F_OUT];   // 3584 dwords = 14 KiB

    const int    tid       = threadIdx.x;
    const size_t cell_base = (size_t)blockIdx.x * CPB;

    // Issue all 4 loads up front for max memory-level parallelism.
    float4 a0 = in[(cell_base + tid) * 2];
    float4 b0 = in[(cell_base + tid) * 2 + 1];
    float4 a1 = in[(cell_base + BLOCK + tid) * 2];
    float4 b1 = in[(cell_base + BLOCK + tid) * 2 + 1];

    #pragma unroll
    for (int j = 0; j < 2; ++j) {
        const int    lc   = tid + j * BLOCK;       // local cell 0..511
        const size_t cell = cell_base + lc;
        const float4 a = j ? a1 : a0;
        const float4 b = j ? b1 : b0;

        const int  g = (int)(cell & (size_t)g_mask);
        const bool m = a.x >= 0.5f;

        const float center = __fmul_rn(__fadd_rn((float)g, a.y), cell_coef);
        const float halfd  = __fmul_rn(__fmul_rn(a.z, unbind_coef), 0.5f);
        const float sv = rintf(__fadd_rn(center, -halfd));  // v_rndne = jnp.round
        const float ev = rintf(__fadd_rn(center,  halfd));

        const float o[F_OUT] = { sv, ev, a.w, b.x, b.y, b.z, b.w };
        #pragma unroll
        for (int k = 0; k < F_OUT; ++k)
            s_frag[lc * F_OUT + k] = m ? o[k] : 0.0f;  // stride-7: 2-way alias, free

        mask_out[cell] = m ? 1.0f : 0.0f;              // stride-1, coalesced
    }

    __syncthreads();

    // frag write-back: 3584 dwords = 896 float4 = 3.5 coalesced b128 sweeps.
    const float4* s4   = (const float4*)s_frag;
    float4*       fdst = (float4*)(frag + cell_base * F_OUT);  // 16B-aligned: blk*14336B
    #pragma unroll
    for (int sweep = 0; sweep < 3; ++sweep)
        fdst[sweep * BLOCK + tid] = s4[sweep * BLOCK + tid];
    if (tid < 128)
        fdst[3 * BLOCK + tid] = s4[3 * BLOCK + tid];
}

extern "C" void kernel_launch(void* const* d_in, const int* in_sizes, int n_in,
                              void* d_out, int out_size, void* d_ws, size_t ws_size,
                              hipStream_t stream) {
    (void)n_in; (void)d_ws; (void)ws_size; (void)out_size;

    const float* x   = (const float*)d_in[0];
    float*       out = (float*)d_out;

    constexpr int F_IN        = 8;
    constexpr int G           = 131072;
    constexpr float INPUT_LEN = 1048576.0f;

    const int total_cells = in_sizes[0] / F_IN;          // 32 * 131072 = 4,194,304
    float* frag = out;                                   // [total_cells * 7]
    float* mask = out + (size_t)total_cells * F_OUT;     // [total_cells]

    const int blocks = total_cells / CPB;                // exact: 8192 blocks

    yolo_decode_kernel<<<blocks, BLOCK, 0, stream>>>(
        (const float4*)x, frag, mask,
        G - 1, INPUT_LEN / (float)G, INPUT_LEN);
}